// Round 18
// baseline (2198.371 us; speedup 1.0000x reference)
//
#include <hip/hip_runtime.h>
#include <math.h>

#define N_NODES 100000
#define N_EDGES 1600000
#define NUM_GRAPHS 128
#define ATOM_IN 92
#define FEA 64
#define EDGE_DIM 41
#define ZDIM 169
#define KPAD 192        // weight rows: 64 h_dst + 64 h_src + 64 ea(pad); row 169 = bias
#define EASTR 48        // bf16 elems stored per edge in eaSb (41 ea + 1.0 + zeros)
#define N_CONV 5
#define HID 256
#define OUT_PER_G 384
#define NPAD 100096      // 391 * 256
#define NBLK 391
#define ESTRIDE 200      // bf16 elems per z row in LDS (192 + 8 pad)
#define BNBLK 250        // BN kernels: 250 blocks x 400 rows

#define HBYTES ((size_t)N_NODES * FEA * 4)   // 25,600,000

typedef __attribute__((ext_vector_type(8))) short bf16x8;
typedef __attribute__((ext_vector_type(4))) float f32x4;
typedef __attribute__((ext_vector_type(16))) float f32x16;

// fast sigmoid: v_rcp instead of full-precision div sequence (~1 ulp, fine
// for bf16-dominated data; absmax margin is 3x)
__device__ __forceinline__ float sigmoidf_(float x) {
    return __builtin_amdgcn_rcpf(1.0f + __expf(-x));
}
__device__ __forceinline__ float softplusf_(float x) {
    float a = fabsf(x);
    return fmaxf(x, 0.0f) + __logf(1.0f + __expf(-a));
}
__device__ __forceinline__ unsigned short f2bf(float f) {
    unsigned int u = __float_as_uint(f);
    u = (u + 0x7FFFu + ((u >> 16) & 1u)) >> 16;   // round-nearest-even
    return (unsigned short)u;
}

// ---------------- embed: h = x @ embW + embB (writes fp32 + bf16 copy) ------
__global__ __launch_bounds__(256) void k_embed(const float* __restrict__ x,
                                               const float* __restrict__ W,
                                               const float* __restrict__ b,
                                               float* __restrict__ h,
                                               unsigned short* __restrict__ hb) {
    int idx = blockIdx.x * 256 + threadIdx.x;
    int c = idx & 63;
    int n = __builtin_amdgcn_readfirstlane(idx >> 6);
    float acc = 0.0f;
#pragma unroll 4
    for (int k = 0; k < ATOM_IN; ++k)
        acc = fmaf(x[n * ATOM_IN + k], W[k * FEA + c], acc);
    acc += b[c];
    h[idx] = acc;
    hb[idx] = f2bf(acc);
}

// ---------------- counting sort of edges by dst (rank-based) ----------------
__global__ __launch_bounds__(256) void k_hist(const int* __restrict__ dst,
                                              int* __restrict__ cnt,
                                              int* __restrict__ rank) {
    int e = blockIdx.x * 256 + threadIdx.x;
    if (e < N_EDGES) rank[e] = atomicAdd(&cnt[dst[e]], 1);
}

__global__ __launch_bounds__(256) void k_blocksum(const int* __restrict__ cnt,
                                                  int* __restrict__ bsum) {
    __shared__ int s[256];
    int t = threadIdx.x;
    s[t] = cnt[blockIdx.x * 256 + t];
    __syncthreads();
    for (int o = 128; o > 0; o >>= 1) {
        if (t < o) s[t] += s[t + o];
        __syncthreads();
    }
    if (t == 0) bsum[blockIdx.x] = s[0];
}

__global__ __launch_bounds__(512) void k_topscan(int* __restrict__ bsum) {
    __shared__ int s[512];
    int t = threadIdx.x;
    int v = (t < NBLK) ? bsum[t] : 0;
    s[t] = v;
    __syncthreads();
    for (int o = 1; o < 512; o <<= 1) {
        int x = (t >= o) ? s[t - o] : 0;
        __syncthreads();
        s[t] += x;
        __syncthreads();
    }
    if (t < NBLK) bsum[t] = s[t] - v;  // exclusive
}

__global__ __launch_bounds__(256) void k_localscan(const int* __restrict__ cnt,
                                                   const int* __restrict__ bsum,
                                                   int* __restrict__ offs) {
    __shared__ int s[256];
    int t = threadIdx.x;
    int i = blockIdx.x * 256 + t;
    int v = cnt[i];
    s[t] = v;
    __syncthreads();
    for (int o = 1; o < 256; o <<= 1) {
        int x = (t >= o) ? s[t - o] : 0;
        __syncthreads();
        s[t] += x;
        __syncthreads();
    }
    offs[i] = bsum[blockIdx.x] + s[t] - v;  // exclusive prefix
}

// dstS filled SEQUENTIALLY from (offs, cnt): contiguous full-line writes.
__global__ __launch_bounds__(256) void k_filldst(const int* __restrict__ offs,
                                                 const int* __restrict__ cnt,
                                                 int* __restrict__ dstS) {
    int n = blockIdx.x * 256 + threadIdx.x;   // < NPAD; cnt==0 for n>=N_NODES
    int p = offs[n];
    for (int e = cnt[n]; e > 0; --e) dstS[p++] = n;
}

// 4B scatters only (srcS, eidS): L2 coalesces ~16 writes/line -> cheap.
__global__ __launch_bounds__(256) void k_scatter_idx(const int* __restrict__ dst,
                                                     const int* __restrict__ src,
                                                     const int* __restrict__ offs,
                                                     const int* __restrict__ rank,
                                                     int* __restrict__ srcS,
                                                     int* __restrict__ eidS) {
    int e = blockIdx.x * 256 + threadIdx.x;   // N_EDGES % 256 == 0
    int d = dst[e];
    int p = offs[d] + rank[e];
    srcS[p] = src[e];
    eidS[p] = e;
}

// eaSb written SEQUENTIALLY (sorted order): gather ea rows (random reads, no
// RMW penalty), convert to bf16 in LDS, block-wide coalesced copy-out.
// Row layout: [0..40]=ea, [41]=1.0 (bias), [42..47]=0.
__global__ __launch_bounds__(256) void k_ea_gather(const float* __restrict__ ea,
                                                   const int* __restrict__ eidS,
                                                   unsigned short* __restrict__ eaSb) {
    __shared__ unsigned short sm[256 * EASTR];   // 24.6 KB
    int t = threadIdx.x;
    int base = blockIdx.x * 256;
    int row = t >> 3, j = t & 7;                 // 32 rows per pass, 8 lanes/row
#pragma unroll
    for (int i = 0; i < 8; ++i) {
        int r = row + i * 32;
        int eid = eidS[base + r];
        const float* srcp = ea + (size_t)eid * EDGE_DIM;
#pragma unroll
        for (int cb = 0; cb < 6; ++cb) {
            int col = j + cb * 8;
            unsigned short v;
            if (col < EDGE_DIM)       v = f2bf(srcp[col]);
            else if (col == EDGE_DIM) v = 0x3F80;   // bf16(1.0)
            else                      v = 0;
            sm[r * EASTR + col] = v;
        }
    }
    __syncthreads();
    const uint4* s4 = (const uint4*)sm;
    uint4* d4 = (uint4*)(eaSb + (size_t)base * EASTR);
    for (int i = t; i < 256 * EASTR * 2 / 16; i += 256) d4[i] = s4[i];
}

// ---------------- weight pack: WbT[L][c][k] = bf16(W[k][c]); row 169 = bias;
// other k>=169 -> 0. c<64 -> Wf/bf col c ; c in [64,128) -> Ws/bs col c-64.
__global__ __launch_bounds__(256) void k_wprep(const float* __restrict__ lfW,
                                               const float* __restrict__ lsW,
                                               const float* __restrict__ lfB,
                                               const float* __restrict__ lsB,
                                               unsigned short* __restrict__ WbT) {
    int idx = blockIdx.x * 256 + threadIdx.x;
    if (idx >= N_CONV * 128 * KPAD) return;
    int k = idx % KPAD;
    int c = (idx / KPAD) % 128;
    int L = idx / (KPAD * 128);
    float v = 0.0f;
    if (k < ZDIM) {
        const float* W = ((c < 64) ? lfW : lsW) + (size_t)L * ZDIM * FEA;
        v = W[k * FEA + (c & 63)];
    } else if (k == ZDIM) {                 // bias row (z[169] == 1.0)
        v = ((c < 64) ? lfB : lsB)[L * FEA + (c & 63)];
    }
    WbT[idx] = f2bf(v);
}

// ---------------- edge kernel: MFMA over z=[h_d|h_s|ea|1|0pad] (bf16) -------
// block = 64 dst-sorted edges, 4 waves (R7/R12 dataflow — measured local
// optimum). R17: GEMM tiling switched to 32x32x16 — wave w owns tile
// (eh=w>>1, ch=w&1): 32 edges x 32 cols for f AND s, 12 K-steps. Halves MFMA
// instruction count (48->24/wave) and A-fragment ds_reads (24->12); B-loads
// stay interleaved with ds_reads+MFMAs (R7-style mix). C/D layout (verified):
// col=lane&31, row=(reg&3)+8*(reg>>2)+4*(lane>>5). A/B: m=lane&31,
// k=8*(lane>>5)+i. Staging / epilogue-math / msg roundtrip / wave-level
// 16-edge run aggregation (one contiguous 64-lane atomic per run) unchanged.
__global__ __launch_bounds__(256) void k_edge(const unsigned short* __restrict__ hb,
                                              const int* __restrict__ dstS,
                                              const int* __restrict__ srcS,
                                              const unsigned short* __restrict__ eaSb,
                                              const unsigned short* __restrict__ WbT,
                                              float* __restrict__ agg) {
    __shared__ unsigned short z[64 * ESTRIDE];   // 25.6 KB; reused as msg
    __shared__ int dsh[64];
    float* msg = (float*)z;                      // [64][66] fp32, 16.9 KB

    int t = threadIdx.x;
    int l = t & 63;
    int w = t >> 6;
    int eb = blockIdx.x * 64;

    if (t < 64) dsh[t] = dstS[eb + t];

    // stage z rows: each thread handles 2 edges x 3 sections (16B chunks).
    // ea section: chunks j<6 from global (48 bf16 stored), j>=6 zero-fill.
    {
        int e0 = (w << 3) + (l >> 3);            // 0..31
        int j = l & 7;
        int d0 = dstS[eb + e0], d1 = dstS[eb + e0 + 32];
        int s0 = srcS[eb + e0], s1 = srcS[eb + e0 + 32];
        *(uint4*)&z[e0 * ESTRIDE + j * 8] =
            *(const uint4*)&hb[(size_t)d0 * 64 + j * 8];
        *(uint4*)&z[(e0 + 32) * ESTRIDE + j * 8] =
            *(const uint4*)&hb[(size_t)d1 * 64 + j * 8];
        *(uint4*)&z[e0 * ESTRIDE + 64 + j * 8] =
            *(const uint4*)&hb[(size_t)s0 * 64 + j * 8];
        *(uint4*)&z[(e0 + 32) * ESTRIDE + 64 + j * 8] =
            *(const uint4*)&hb[(size_t)s1 * 64 + j * 8];
        if (j < 6) {
            *(uint4*)&z[e0 * ESTRIDE + 128 + j * 8] =
                *(const uint4*)&eaSb[(size_t)(eb + e0) * EASTR + j * 8];
            *(uint4*)&z[(e0 + 32) * ESTRIDE + 128 + j * 8] =
                *(const uint4*)&eaSb[(size_t)(eb + e0 + 32) * EASTR + j * 8];
        } else {
            uint4 zr = make_uint4(0u, 0u, 0u, 0u);
            *(uint4*)&z[e0 * ESTRIDE + 128 + j * 8] = zr;
            *(uint4*)&z[(e0 + 32) * ESTRIDE + 128 + j * 8] = zr;
        }
    }
    __syncthreads();

    // MFMA 32x32x16: wave w -> edges [32eh,32eh+32) x cols [32ch,32ch+32),
    // f AND s. 12 K-steps, 24 MFMA, 12 A ds_reads.
    int l31 = l & 31, lhi = l >> 5;              // A/B: m|n=lane&31, k=8*lhi+i
    int eh = w >> 1;                             // 0..1 edge-half
    int ch = w & 1;                              // 0..1 col-half
    int colB = ch * 32 + l31;
    const unsigned short* WF = WbT + (size_t)colB * KPAD;
    const unsigned short* WS = WbT + (size_t)(64 + colB) * KPAD;
    f32x16 accF = {};
    f32x16 accS = {};
#pragma unroll
    for (int ks = 0; ks < 12; ++ks) {
        int kofs = ks * 16 + lhi * 8;
        bf16x8 a = *(const bf16x8*)&z[(eh * 32 + l31) * ESTRIDE + kofs];
        bf16x8 bF = *(const bf16x8*)&WF[kofs];
        bf16x8 bS = *(const bf16x8*)&WS[kofs];
        accF = __builtin_amdgcn_mfma_f32_32x32x16_bf16(a, bF, accF, 0, 0, 0);
        accS = __builtin_amdgcn_mfma_f32_32x32x16_bf16(a, bS, accS, 0, 0, 0);
    }
    __syncthreads();   // all waves done reading z; msg region live

    // epilogue in-register (bias already in acc), publish msg to LDS.
    // acc reg q -> edge e = 32eh + (q&3) + 8*(q>>2) + 4*lhi, col = colB.
#pragma unroll
    for (int q = 0; q < 16; ++q) {
        int e = 32 * eh + (q & 3) + 8 * (q >> 2) + 4 * lhi;
        msg[e * 66 + colB] = sigmoidf_(accF[q]) * softplusf_(accS[q]);
    }
    __syncthreads();

    // aggregation: wave w -> edges [16w,16w+16), lane = column.
    // run boundaries via one ballot; one contiguous 64-lane atomic per run.
    {
        int e0 = w * 16;
        bool bnd = (l < 15) && (dsh[e0 + l] != dsh[e0 + l + 1]);
        unsigned long long bm = __ballot(bnd) | (1ull << 15);
        float a = 0.0f;
#pragma unroll
        for (int i = 0; i < 16; ++i) {
            a += msg[(e0 + i) * 66 + l];
            if (bm & (1ull << i)) {
                atomicAdd(&agg[(size_t)dsh[e0 + i] * FEA + l], a);
                a = 0.0f;
            }
        }
    }
}

// ---------------- BN stats / apply ----------------
__global__ __launch_bounds__(256) void k_bnstats(const float* __restrict__ agg,
                                                 float* __restrict__ stats) {
    int t = threadIdx.x, c = t & 63, w = t >> 6;
    int r0 = blockIdx.x * 400;
    float s = 0.0f, q = 0.0f;
    for (int r = r0 + w; r < r0 + 400; r += 4) {
        float v = agg[(size_t)r * FEA + c];
        s += v;
        q = fmaf(v, v, q);
    }
    __shared__ float red[2][256];
    red[0][t] = s;
    red[1][t] = q;
    __syncthreads();
    if (t < 64) {
        s = red[0][t] + red[0][t + 64] + red[0][t + 128] + red[0][t + 192];
        q = red[1][t] + red[1][t + 64] + red[1][t + 128] + red[1][t + 192];
        atomicAdd(&stats[t], s);
        atomicAdd(&stats[64 + t], q);
    }
}

// h += BN(agg); re-zeroes agg (agg's last reader). float4/ushort4 vectorized.
__global__ __launch_bounds__(256) void k_bnapply(float* __restrict__ agg,
                                                 const float* __restrict__ stats,
                                                 const float* __restrict__ gamma,
                                                 const float* __restrict__ beta,
                                                 float* __restrict__ h,
                                                 unsigned short* __restrict__ hb) {
    int t = threadIdx.x;
    size_t base4 = (size_t)blockIdx.x * 6400;   // float4 units; 400 rows x 16
    for (int i = t; i < 6400; i += 256) {
        size_t idx = (base4 + i) * 4;
        int c0 = (int)(idx & 63);
        float4 v = *(float4*)&agg[idx];
        *(float4*)&agg[idx] = make_float4(0.f, 0.f, 0.f, 0.f);
        float4 hv = *(float4*)&h[idx];
        float o[4];
        unsigned short ob[4];
#pragma unroll
        for (int k = 0; k < 4; ++k) {
            int c = c0 + k;
            float mu = stats[c] * (1.0f / N_NODES);
            float var = stats[64 + c] * (1.0f / N_NODES) - mu * mu;
            float rs = rsqrtf(var + 1e-5f);
            float vk = (k == 0) ? v.x : (k == 1) ? v.y : (k == 2) ? v.z : v.w;
            float hk = (k == 0) ? hv.x : (k == 1) ? hv.y : (k == 2) ? hv.z : hv.w;
            float hn = hk + (vk - mu) * rs * gamma[c] + beta[c];
            o[k] = hn;
            ob[k] = f2bf(hn);
        }
        *(float4*)&h[idx] = make_float4(o[0], o[1], o[2], o[3]);
        *(uint2*)&hb[idx] = *(uint2*)ob;
    }
}

// ---------------- pool + head ----------------
__global__ __launch_bounds__(256) void k_pool(const float* __restrict__ h,
                                              const int* __restrict__ batch,
                                              float* __restrict__ psum,
                                              float* __restrict__ pcnt) {
    int g = blockIdx.x;
    int lo, hi;
    {
        int a = 0, b = N_NODES;
        while (a < b) { int m = (a + b) >> 1; if (batch[m] < g) a = m + 1; else b = m; }
        lo = a;
    }
    {
        int a = lo, b = N_NODES;
        while (a < b) { int m = (a + b) >> 1; if (batch[m] < g + 1) a = m + 1; else b = m; }
        hi = a;
    }
    int t = threadIdx.x, c = t & 63, w = t >> 6;
    float s = 0.0f;
    for (int r = lo + w; r < hi; r += 4) s += h[(size_t)r * FEA + c];
    __shared__ float red[256];
    red[t] = s;
    __syncthreads();
    if (t < 64) {
        psum[g * FEA + t] = red[t] + red[t + 64] + red[t + 128] + red[t + 192];
        if (t == 0) pcnt[g] = (float)(hi - lo);
    }
}

__global__ __launch_bounds__(256) void k_head(const float* __restrict__ psum,
                                              const float* __restrict__ pcnt,
                                              const float* __restrict__ W1, const float* __restrict__ b1,
                                              const float* __restrict__ W2, const float* __restrict__ b2,
                                              const float* __restrict__ W3, const float* __restrict__ b3,
                                              float* __restrict__ out) {
    int g = blockIdx.x, t = threadIdx.x;
    __shared__ float p[64], g1[256], g2[256];
    if (t < 64) p[t] = psum[g * FEA + t] / fmaxf(pcnt[g], 1.0f);
    __syncthreads();
    {
        float acc = b1[t];
#pragma unroll 8
        for (int k = 0; k < FEA; ++k) acc = fmaf(p[k], W1[k * HID + t], acc);
        g1[t] = softplusf_(acc);
    }
    __syncthreads();
    {
        float acc = b2[t];
#pragma unroll 8
        for (int k = 0; k < HID; ++k) acc = fmaf(g1[k], W2[k * HID + t], acc);
        g2[t] = softplusf_(acc);
    }
    __syncthreads();
    for (int c = t; c < OUT_PER_G; c += 256) {
        float acc = b3[c];
#pragma unroll 8
        for (int k = 0; k < HID; ++k) acc = fmaf(g2[k], W3[k * OUT_PER_G + c], acc);
        out[g * OUT_PER_G + c] = acc;
    }
}

extern "C" void kernel_launch(void* const* d_in, const int* in_sizes, int n_in,
                              void* d_out, int out_size, void* d_ws, size_t ws_size,
                              hipStream_t stream) {
    (void)in_sizes; (void)n_in; (void)out_size; (void)ws_size;
    const float* x    = (const float*)d_in[0];
    const int*   ei   = (const int*)d_in[1];
    const float* ea   = (const float*)d_in[2];
    const int*   batch= (const int*)d_in[3];
    const float* embW = (const float*)d_in[4];
    const float* embB = (const float*)d_in[5];
    const float* lfW  = (const float*)d_in[6];
    const float* lfB  = (const float*)d_in[7];
    const float* lsW  = (const float*)d_in[8];
    const float* lsB  = (const float*)d_in[9];
    const float* gam  = (const float*)d_in[10];
    const float* bet  = (const float*)d_in[11];
    const float* W1 = (const float*)d_in[12];
    const float* b1 = (const float*)d_in[13];
    const float* W2 = (const float*)d_in[14];
    const float* b2 = (const float*)d_in[15];
    const float* W3 = (const float*)d_in[16];
    const float* b3 = (const float*)d_in[17];

    const int* srcI = ei;             // edge_index[0] = source (x_j)
    const int* dstI = ei + N_EDGES;   // edge_index[1] = target (x_i)

    char* ws = (char*)d_ws;
    size_t off = 0;
    float* h      = (float*)(ws + off); off += HBYTES;                   // 25.6 MB
    float* agg    = (float*)(ws + off); off += HBYTES;                   // 25.6 MB
    float* stats  = (float*)(ws + off); off += 5 * 512;                  // 5 layer slots; joint memset w/ agg
    float* psum   = (float*)(ws + off); off += 32768;
    float* pcnt   = (float*)(ws + off); off += 512;
    unsigned short* hbuf = (unsigned short*)(ws + off); off += (size_t)N_NODES * 64 * 2;      // 12.8 MB
    unsigned short* eaSb = (unsigned short*)(ws + off); off += (size_t)N_EDGES * EASTR * 2;   // 153.6 MB
    unsigned short* WbT  = (unsigned short*)(ws + off); off += (size_t)N_CONV * 128 * KPAD * 2;
    int*   cnt    = (int*)(ws + off);   off += (size_t)NPAD * 4;
    int*   bsum   = (int*)(ws + off);   off += 2048;
    int*   offs   = (int*)(ws + off);   off += (size_t)NPAD * 4;
    int*   rank   = (int*)(ws + off);   off += (size_t)N_EDGES * 4;
    int*   dstS   = (int*)(ws + off);   off += (size_t)N_EDGES * 4;
    int*   srcS   = (int*)(ws + off);   off += (size_t)N_EDGES * 4;
    int*   eidS   = (int*)(ws + off);   off += (size_t)N_EDGES * 4;

    // ---- one-time per launch: sort edges by dst, gather ea sorted, pack W ----
    hipMemsetAsync(cnt, 0, (size_t)NPAD * 4, stream);
    k_hist<<<(N_EDGES + 255) / 256, 256, 0, stream>>>(dstI, cnt, rank);
    k_blocksum<<<NBLK, 256, 0, stream>>>(cnt, bsum);
    k_topscan<<<1, 512, 0, stream>>>(bsum);
    k_localscan<<<NBLK, 256, 0, stream>>>(cnt, bsum, offs);
    k_filldst<<<NBLK, 256, 0, stream>>>(offs, cnt, dstS);
    k_scatter_idx<<<N_EDGES / 256, 256, 0, stream>>>(dstI, srcI, offs, rank,
                                                     srcS, eidS);
    k_ea_gather<<<N_EDGES / 256, 256, 0, stream>>>(ea, eidS, eaSb);
    k_wprep<<<(N_CONV * 128 * KPAD + 255) / 256, 256, 0, stream>>>(lfW, lsW,
                                                                   lfB, lsB, WbT);

    k_embed<<<N_NODES * FEA / 256, 256, 0, stream>>>(x, embW, embB, h, hbuf);

    // agg + all 5 stats slots zeroed once (covers harness poison); thereafter
    // k_bnapply re-zeroes agg and each layer uses its own stats slot.
    hipMemsetAsync(agg, 0, HBYTES + 5 * 512, stream);

    for (int L = 0; L < N_CONV; ++L) {
        k_edge<<<N_EDGES / 64, 256, 0, stream>>>(hbuf, dstS, srcS, eaSb,
                                                 WbT + (size_t)L * 128 * KPAD,
                                                 agg);
        k_bnstats<<<BNBLK, 256, 0, stream>>>(agg, stats + L * 128);
        k_bnapply<<<BNBLK, 256, 0, stream>>>(agg, stats + L * 128,
                                             gam + L * FEA, bet + L * FEA,
                                             h, hbuf);
    }

    k_pool<<<NUM_GRAPHS, 256, 0, stream>>>(h, batch, psum, pcnt);
    k_head<<<NUM_GRAPHS, 256, 0, stream>>>(psum, pcnt, W1, b1, W2, b2, W3, b3,
                                           (float*)d_out);
}

// Round 19
// 1557.508 us; speedup vs baseline: 1.4115x; 1.4115x over previous
//
#include <hip/hip_runtime.h>
#include <math.h>

#define N_NODES 100000
#define N_EDGES 1600000
#define NUM_GRAPHS 128
#define ATOM_IN 92
#define FEA 64
#define EDGE_DIM 41
#define ZDIM 169
#define KPAD 192        // weight rows: 64 h_dst + 64 h_src + 64 ea(pad); row 169 = bias
#define EASTR 48        // bf16 elems stored per edge in eaSb (41 ea + 1.0 + zeros)
#define N_CONV 5
#define HID 256
#define OUT_PER_G 384
#define NPAD 100096      // 391 * 256
#define NBLK 391
#define ESTRIDE 200      // bf16 elems per z row in LDS (192 + 8 pad)
#define BNBLK 250        // BN kernels: 250 blocks x 400 rows

#define HBYTES ((size_t)N_NODES * FEA * 4)   // 25,600,000

typedef __attribute__((ext_vector_type(8))) short bf16x8;
typedef __attribute__((ext_vector_type(4))) float f32x4;

// fast sigmoid: v_rcp instead of full-precision div sequence (~1 ulp, fine
// for bf16-dominated data; absmax margin is 3x)
__device__ __forceinline__ float sigmoidf_(float x) {
    return __builtin_amdgcn_rcpf(1.0f + __expf(-x));
}
__device__ __forceinline__ float softplusf_(float x) {
    float a = fabsf(x);
    return fmaxf(x, 0.0f) + __logf(1.0f + __expf(-a));
}
__device__ __forceinline__ unsigned short f2bf(float f) {
    unsigned int u = __float_as_uint(f);
    u = (u + 0x7FFFu + ((u >> 16) & 1u)) >> 16;   // round-nearest-even
    return (unsigned short)u;
}

// ---------------- embed: h = x @ embW + embB (writes fp32 + bf16 copy) ------
__global__ __launch_bounds__(256) void k_embed(const float* __restrict__ x,
                                               const float* __restrict__ W,
                                               const float* __restrict__ b,
                                               float* __restrict__ h,
                                               unsigned short* __restrict__ hb) {
    int idx = blockIdx.x * 256 + threadIdx.x;
    int c = idx & 63;
    int n = __builtin_amdgcn_readfirstlane(idx >> 6);
    float acc = 0.0f;
#pragma unroll 4
    for (int k = 0; k < ATOM_IN; ++k)
        acc = fmaf(x[n * ATOM_IN + k], W[k * FEA + c], acc);
    acc += b[c];
    h[idx] = acc;
    hb[idx] = f2bf(acc);
}

// ---------------- counting sort of edges by dst (rank-based) ----------------
__global__ __launch_bounds__(256) void k_hist(const int* __restrict__ dst,
                                              int* __restrict__ cnt,
                                              int* __restrict__ rank) {
    int e = blockIdx.x * 256 + threadIdx.x;
    if (e < N_EDGES) rank[e] = atomicAdd(&cnt[dst[e]], 1);
}

__global__ __launch_bounds__(256) void k_blocksum(const int* __restrict__ cnt,
                                                  int* __restrict__ bsum) {
    __shared__ int s[256];
    int t = threadIdx.x;
    s[t] = cnt[blockIdx.x * 256 + t];
    __syncthreads();
    for (int o = 128; o > 0; o >>= 1) {
        if (t < o) s[t] += s[t + o];
        __syncthreads();
    }
    if (t == 0) bsum[blockIdx.x] = s[0];
}

__global__ __launch_bounds__(512) void k_topscan(int* __restrict__ bsum) {
    __shared__ int s[512];
    int t = threadIdx.x;
    int v = (t < NBLK) ? bsum[t] : 0;
    s[t] = v;
    __syncthreads();
    for (int o = 1; o < 512; o <<= 1) {
        int x = (t >= o) ? s[t - o] : 0;
        __syncthreads();
        s[t] += x;
        __syncthreads();
    }
    if (t < NBLK) bsum[t] = s[t] - v;  // exclusive
}

__global__ __launch_bounds__(256) void k_localscan(const int* __restrict__ cnt,
                                                   const int* __restrict__ bsum,
                                                   int* __restrict__ offs) {
    __shared__ int s[256];
    int t = threadIdx.x;
    int i = blockIdx.x * 256 + t;
    int v = cnt[i];
    s[t] = v;
    __syncthreads();
    for (int o = 1; o < 256; o <<= 1) {
        int x = (t >= o) ? s[t - o] : 0;
        __syncthreads();
        s[t] += x;
        __syncthreads();
    }
    offs[i] = bsum[blockIdx.x] + s[t] - v;  // exclusive prefix
}

// dstS filled SEQUENTIALLY from (offs, cnt): contiguous full-line writes.
__global__ __launch_bounds__(256) void k_filldst(const int* __restrict__ offs,
                                                 const int* __restrict__ cnt,
                                                 int* __restrict__ dstS) {
    int n = blockIdx.x * 256 + threadIdx.x;   // < NPAD; cnt==0 for n>=N_NODES
    int p = offs[n];
    for (int e = cnt[n]; e > 0; --e) dstS[p++] = n;
}

// 4B scatters only (srcS, eidS): L2 coalesces ~16 writes/line -> cheap.
__global__ __launch_bounds__(256) void k_scatter_idx(const int* __restrict__ dst,
                                                     const int* __restrict__ src,
                                                     const int* __restrict__ offs,
                                                     const int* __restrict__ rank,
                                                     int* __restrict__ srcS,
                                                     int* __restrict__ eidS) {
    int e = blockIdx.x * 256 + threadIdx.x;   // N_EDGES % 256 == 0
    int d = dst[e];
    int p = offs[d] + rank[e];
    srcS[p] = src[e];
    eidS[p] = e;
}

// eaSb written SEQUENTIALLY (sorted order): gather ea rows (random reads, no
// RMW penalty), convert to bf16 in LDS, block-wide coalesced copy-out.
// Row layout: [0..40]=ea, [41]=1.0 (bias), [42..47]=0.
__global__ __launch_bounds__(256) void k_ea_gather(const float* __restrict__ ea,
                                                   const int* __restrict__ eidS,
                                                   unsigned short* __restrict__ eaSb) {
    __shared__ unsigned short sm[256 * EASTR];   // 24.6 KB
    int t = threadIdx.x;
    int base = blockIdx.x * 256;
    int row = t >> 3, j = t & 7;                 // 32 rows per pass, 8 lanes/row
#pragma unroll
    for (int i = 0; i < 8; ++i) {
        int r = row + i * 32;
        int eid = eidS[base + r];
        const float* srcp = ea + (size_t)eid * EDGE_DIM;
#pragma unroll
        for (int cb = 0; cb < 6; ++cb) {
            int col = j + cb * 8;
            unsigned short v;
            if (col < EDGE_DIM)       v = f2bf(srcp[col]);
            else if (col == EDGE_DIM) v = 0x3F80;   // bf16(1.0)
            else                      v = 0;
            sm[r * EASTR + col] = v;
        }
    }
    __syncthreads();
    const uint4* s4 = (const uint4*)sm;
    uint4* d4 = (uint4*)(eaSb + (size_t)base * EASTR);
    for (int i = t; i < 256 * EASTR * 2 / 16; i += 256) d4[i] = s4[i];
}

// ---------------- weight pack: WbT[L][c][k] = bf16(W[k][c]); row 169 = bias;
// other k>=169 -> 0. c<64 -> Wf/bf col c ; c in [64,128) -> Ws/bs col c-64.
__global__ __launch_bounds__(256) void k_wprep(const float* __restrict__ lfW,
                                               const float* __restrict__ lsW,
                                               const float* __restrict__ lfB,
                                               const float* __restrict__ lsB,
                                               unsigned short* __restrict__ WbT) {
    int idx = blockIdx.x * 256 + threadIdx.x;
    if (idx >= N_CONV * 128 * KPAD) return;
    int k = idx % KPAD;
    int c = (idx / KPAD) % 128;
    int L = idx / (KPAD * 128);
    float v = 0.0f;
    if (k < ZDIM) {
        const float* W = ((c < 64) ? lfW : lsW) + (size_t)L * ZDIM * FEA;
        v = W[k * FEA + (c & 63)];
    } else if (k == ZDIM) {                 // bias row (z[169] == 1.0)
        v = ((c < 64) ? lfB : lsB)[L * FEA + (c & 63)];
    }
    WbT[idx] = f2bf(v);
}

// ---------------- edge kernel: MFMA over z=[h_d|h_s|ea|1|0pad] (bf16) -------
// block = 64 dst-sorted edges, 4 waves (R7/R12 structure — measured local
// optimum; R5/R8/R9/R14/R15/R17 neighbors all regressed). Wave w owns output
// cols [16w,16w+16) for BOTH f and s (8 independent acc chains hide MFMA
// latency); bias folded into W row 169. Full LDS staging (MFMA operands never
// from global). msg via LDS; wave-level 16-edge run aggregation, one
// contiguous 64-lane atomic per run. Ballot run boundaries.
__global__ __launch_bounds__(256) void k_edge(const unsigned short* __restrict__ hb,
                                              const int* __restrict__ dstS,
                                              const int* __restrict__ srcS,
                                              const unsigned short* __restrict__ eaSb,
                                              const unsigned short* __restrict__ WbT,
                                              float* __restrict__ agg) {
    __shared__ unsigned short z[64 * ESTRIDE];   // 25.6 KB; reused as msg
    __shared__ int dsh[64];
    float* msg = (float*)z;                      // [64][66] fp32, 16.9 KB

    int t = threadIdx.x;
    int l = t & 63;
    int w = t >> 6;
    int eb = blockIdx.x * 64;

    if (t < 64) dsh[t] = dstS[eb + t];

    // stage z rows: each thread handles 2 edges x 3 sections (16B chunks).
    // ea section: chunks j<6 from global (48 bf16 stored), j>=6 zero-fill.
    {
        int e0 = (w << 3) + (l >> 3);            // 0..31
        int j = l & 7;
        int d0 = dstS[eb + e0], d1 = dstS[eb + e0 + 32];
        int s0 = srcS[eb + e0], s1 = srcS[eb + e0 + 32];
        *(uint4*)&z[e0 * ESTRIDE + j * 8] =
            *(const uint4*)&hb[(size_t)d0 * 64 + j * 8];
        *(uint4*)&z[(e0 + 32) * ESTRIDE + j * 8] =
            *(const uint4*)&hb[(size_t)d1 * 64 + j * 8];
        *(uint4*)&z[e0 * ESTRIDE + 64 + j * 8] =
            *(const uint4*)&hb[(size_t)s0 * 64 + j * 8];
        *(uint4*)&z[(e0 + 32) * ESTRIDE + 64 + j * 8] =
            *(const uint4*)&hb[(size_t)s1 * 64 + j * 8];
        if (j < 6) {
            *(uint4*)&z[e0 * ESTRIDE + 128 + j * 8] =
                *(const uint4*)&eaSb[(size_t)(eb + e0) * EASTR + j * 8];
            *(uint4*)&z[(e0 + 32) * ESTRIDE + 128 + j * 8] =
                *(const uint4*)&eaSb[(size_t)(eb + e0 + 32) * EASTR + j * 8];
        } else {
            uint4 zr = make_uint4(0u, 0u, 0u, 0u);
            *(uint4*)&z[e0 * ESTRIDE + 128 + j * 8] = zr;
            *(uint4*)&z[(e0 + 32) * ESTRIDE + 128 + j * 8] = zr;
        }
    }
    __syncthreads();

    // MFMA: per wave, C[64 e][16 cols] for f AND s. 4 row-tiles x 6 K-steps.
    int lm = l & 15, lg = l >> 4;
    int col = w * 16 + lm;
    const unsigned short* WF = WbT + (size_t)col * KPAD;
    const unsigned short* WS = WbT + (size_t)(64 + col) * KPAD;
    f32x4 accF[4] = {};
    f32x4 accS[4] = {};
#pragma unroll
    for (int ks = 0; ks < 6; ++ks) {
        int kofs = ks * 32 + lg * 8;
        bf16x8 a[4];
#pragma unroll
        for (int r = 0; r < 4; ++r)
            a[r] = *(const bf16x8*)&z[(16 * r + lm) * ESTRIDE + kofs];
        bf16x8 bF = *(const bf16x8*)&WF[kofs];
        bf16x8 bS = *(const bf16x8*)&WS[kofs];
#pragma unroll
        for (int r = 0; r < 4; ++r) {
            accF[r] = __builtin_amdgcn_mfma_f32_16x16x32_bf16(a[r], bF, accF[r], 0, 0, 0);
            accS[r] = __builtin_amdgcn_mfma_f32_16x16x32_bf16(a[r], bS, accS[r], 0, 0, 0);
        }
    }
    __syncthreads();   // all waves done reading z; msg region live

    // epilogue in-register (bias already in acc), publish msg to LDS.
    // acc element (r,j) -> edge e = 16r + 4*lg + j, this thread's col.
#pragma unroll
    for (int r = 0; r < 4; ++r)
#pragma unroll
        for (int j = 0; j < 4; ++j) {
            int e = 16 * r + 4 * lg + j;
            msg[e * 66 + col] = sigmoidf_(accF[r][j]) * softplusf_(accS[r][j]);
        }
    __syncthreads();

    // aggregation: wave w -> edges [16w,16w+16), lane = column.
    // run boundaries via one ballot; one contiguous 64-lane atomic per run.
    {
        int e0 = w * 16;
        bool bnd = (l < 15) && (dsh[e0 + l] != dsh[e0 + l + 1]);
        unsigned long long bm = __ballot(bnd) | (1ull << 15);
        float a = 0.0f;
#pragma unroll
        for (int i = 0; i < 16; ++i) {
            a += msg[(e0 + i) * 66 + l];
            if (bm & (1ull << i)) {
                atomicAdd(&agg[(size_t)dsh[e0 + i] * FEA + l], a);
                a = 0.0f;
            }
        }
    }
}

// ---------------- BN stats / apply ----------------
__global__ __launch_bounds__(256) void k_bnstats(const float* __restrict__ agg,
                                                 float* __restrict__ stats) {
    int t = threadIdx.x, c = t & 63, w = t >> 6;
    int r0 = blockIdx.x * 400;
    float s = 0.0f, q = 0.0f;
    for (int r = r0 + w; r < r0 + 400; r += 4) {
        float v = agg[(size_t)r * FEA + c];
        s += v;
        q = fmaf(v, v, q);
    }
    __shared__ float red[2][256];
    red[0][t] = s;
    red[1][t] = q;
    __syncthreads();
    if (t < 64) {
        s = red[0][t] + red[0][t + 64] + red[0][t + 128] + red[0][t + 192];
        q = red[1][t] + red[1][t + 64] + red[1][t + 128] + red[1][t + 192];
        atomicAdd(&stats[t], s);
        atomicAdd(&stats[64 + t], q);
    }
}

// h += BN(agg); re-zeroes agg (agg's last reader). float4/ushort4 vectorized.
__global__ __launch_bounds__(256) void k_bnapply(float* __restrict__ agg,
                                                 const float* __restrict__ stats,
                                                 const float* __restrict__ gamma,
                                                 const float* __restrict__ beta,
                                                 float* __restrict__ h,
                                                 unsigned short* __restrict__ hb) {
    int t = threadIdx.x;
    size_t base4 = (size_t)blockIdx.x * 6400;   // float4 units; 400 rows x 16
    for (int i = t; i < 6400; i += 256) {
        size_t idx = (base4 + i) * 4;
        int c0 = (int)(idx & 63);
        float4 v = *(float4*)&agg[idx];
        *(float4*)&agg[idx] = make_float4(0.f, 0.f, 0.f, 0.f);
        float4 hv = *(float4*)&h[idx];
        float o[4];
        unsigned short ob[4];
#pragma unroll
        for (int k = 0; k < 4; ++k) {
            int c = c0 + k;
            float mu = stats[c] * (1.0f / N_NODES);
            float var = stats[64 + c] * (1.0f / N_NODES) - mu * mu;
            float rs = rsqrtf(var + 1e-5f);
            float vk = (k == 0) ? v.x : (k == 1) ? v.y : (k == 2) ? v.z : v.w;
            float hk = (k == 0) ? hv.x : (k == 1) ? hv.y : (k == 2) ? hv.z : hv.w;
            float hn = hk + (vk - mu) * rs * gamma[c] + beta[c];
            o[k] = hn;
            ob[k] = f2bf(hn);
        }
        *(float4*)&h[idx] = make_float4(o[0], o[1], o[2], o[3]);
        *(uint2*)&hb[idx] = *(uint2*)ob;
    }
}

// ---------------- pool + head ----------------
__global__ __launch_bounds__(256) void k_pool(const float* __restrict__ h,
                                              const int* __restrict__ batch,
                                              float* __restrict__ psum,
                                              float* __restrict__ pcnt) {
    int g = blockIdx.x;
    int lo, hi;
    {
        int a = 0, b = N_NODES;
        while (a < b) { int m = (a + b) >> 1; if (batch[m] < g) a = m + 1; else b = m; }
        lo = a;
    }
    {
        int a = lo, b = N_NODES;
        while (a < b) { int m = (a + b) >> 1; if (batch[m] < g + 1) a = m + 1; else b = m; }
        hi = a;
    }
    int t = threadIdx.x, c = t & 63, w = t >> 6;
    float s = 0.0f;
    for (int r = lo + w; r < hi; r += 4) s += h[(size_t)r * FEA + c];
    __shared__ float red[256];
    red[t] = s;
    __syncthreads();
    if (t < 64) {
        psum[g * FEA + t] = red[t] + red[t + 64] + red[t + 128] + red[t + 192];
        if (t == 0) pcnt[g] = (float)(hi - lo);
    }
}

__global__ __launch_bounds__(256) void k_head(const float* __restrict__ psum,
                                              const float* __restrict__ pcnt,
                                              const float* __restrict__ W1, const float* __restrict__ b1,
                                              const float* __restrict__ W2, const float* __restrict__ b2,
                                              const float* __restrict__ W3, const float* __restrict__ b3,
                                              float* __restrict__ out) {
    int g = blockIdx.x, t = threadIdx.x;
    __shared__ float p[64], g1[256], g2[256];
    if (t < 64) p[t] = psum[g * FEA + t] / fmaxf(pcnt[g], 1.0f);
    __syncthreads();
    {
        float acc = b1[t];
#pragma unroll 8
        for (int k = 0; k < FEA; ++k) acc = fmaf(p[k], W1[k * HID + t], acc);
        g1[t] = softplusf_(acc);
    }
    __syncthreads();
    {
        float acc = b2[t];
#pragma unroll 8
        for (int k = 0; k < HID; ++k) acc = fmaf(g1[k], W2[k * HID + t], acc);
        g2[t] = softplusf_(acc);
    }
    __syncthreads();
    for (int c = t; c < OUT_PER_G; c += 256) {
        float acc = b3[c];
#pragma unroll 8
        for (int k = 0; k < HID; ++k) acc = fmaf(g2[k], W3[k * OUT_PER_G + c], acc);
        out[g * OUT_PER_G + c] = acc;
    }
}

extern "C" void kernel_launch(void* const* d_in, const int* in_sizes, int n_in,
                              void* d_out, int out_size, void* d_ws, size_t ws_size,
                              hipStream_t stream) {
    (void)in_sizes; (void)n_in; (void)out_size; (void)ws_size;
    const float* x    = (const float*)d_in[0];
    const int*   ei   = (const int*)d_in[1];
    const float* ea   = (const float*)d_in[2];
    const int*   batch= (const int*)d_in[3];
    const float* embW = (const float*)d_in[4];
    const float* embB = (const float*)d_in[5];
    const float* lfW  = (const float*)d_in[6];
    const float* lfB  = (const float*)d_in[7];
    const float* lsW  = (const float*)d_in[8];
    const float* lsB  = (const float*)d_in[9];
    const float* gam  = (const float*)d_in[10];
    const float* bet  = (const float*)d_in[11];
    const float* W1 = (const float*)d_in[12];
    const float* b1 = (const float*)d_in[13];
    const float* W2 = (const float*)d_in[14];
    const float* b2 = (const float*)d_in[15];
    const float* W3 = (const float*)d_in[16];
    const float* b3 = (const float*)d_in[17];

    const int* srcI = ei;             // edge_index[0] = source (x_j)
    const int* dstI = ei + N_EDGES;   // edge_index[1] = target (x_i)

    char* ws = (char*)d_ws;
    size_t off = 0;
    float* h      = (float*)(ws + off); off += HBYTES;                   // 25.6 MB
    float* agg    = (float*)(ws + off); off += HBYTES;                   // 25.6 MB
    float* stats  = (float*)(ws + off); off += 5 * 512;                  // 5 layer slots; joint memset w/ agg
    float* psum   = (float*)(ws + off); off += 32768;
    float* pcnt   = (float*)(ws + off); off += 512;
    unsigned short* hbuf = (unsigned short*)(ws + off); off += (size_t)N_NODES * 64 * 2;      // 12.8 MB
    unsigned short* eaSb = (unsigned short*)(ws + off); off += (size_t)N_EDGES * EASTR * 2;   // 153.6 MB
    unsigned short* WbT  = (unsigned short*)(ws + off); off += (size_t)N_CONV * 128 * KPAD * 2;
    int*   cnt    = (int*)(ws + off);   off += (size_t)NPAD * 4;
    int*   bsum   = (int*)(ws + off);   off += 2048;
    int*   offs   = (int*)(ws + off);   off += (size_t)NPAD * 4;
    int*   rank   = (int*)(ws + off);   off += (size_t)N_EDGES * 4;
    int*   dstS   = (int*)(ws + off);   off += (size_t)N_EDGES * 4;
    int*   srcS   = (int*)(ws + off);   off += (size_t)N_EDGES * 4;
    int*   eidS   = (int*)(ws + off);   off += (size_t)N_EDGES * 4;

    // ---- one-time per launch: sort edges by dst, gather ea sorted, pack W ----
    hipMemsetAsync(cnt, 0, (size_t)NPAD * 4, stream);
    k_hist<<<(N_EDGES + 255) / 256, 256, 0, stream>>>(dstI, cnt, rank);
    k_blocksum<<<NBLK, 256, 0, stream>>>(cnt, bsum);
    k_topscan<<<1, 512, 0, stream>>>(bsum);
    k_localscan<<<NBLK, 256, 0, stream>>>(cnt, bsum, offs);
    k_filldst<<<NBLK, 256, 0, stream>>>(offs, cnt, dstS);
    k_scatter_idx<<<N_EDGES / 256, 256, 0, stream>>>(dstI, srcI, offs, rank,
                                                     srcS, eidS);
    k_ea_gather<<<N_EDGES / 256, 256, 0, stream>>>(ea, eidS, eaSb);
    k_wprep<<<(N_CONV * 128 * KPAD + 255) / 256, 256, 0, stream>>>(lfW, lsW,
                                                                   lfB, lsB, WbT);

    k_embed<<<N_NODES * FEA / 256, 256, 0, stream>>>(x, embW, embB, h, hbuf);

    // agg + all 5 stats slots zeroed once (covers harness poison); thereafter
    // k_bnapply re-zeroes agg and each layer uses its own stats slot.
    hipMemsetAsync(agg, 0, HBYTES + 5 * 512, stream);

    for (int L = 0; L < N_CONV; ++L) {
        k_edge<<<N_EDGES / 64, 256, 0, stream>>>(hbuf, dstS, srcS, eaSb,
                                                 WbT + (size_t)L * 128 * KPAD,
                                                 agg);
        k_bnstats<<<BNBLK, 256, 0, stream>>>(agg, stats + L * 128);
        k_bnapply<<<BNBLK, 256, 0, stream>>>(agg, stats + L * 128,
                                             gam + L * FEA, bet + L * FEA,
                                             h, hbuf);
    }

    k_pool<<<NUM_GRAPHS, 256, 0, stream>>>(h, batch, psum, pcnt);
    k_head<<<NUM_GRAPHS, 256, 0, stream>>>(psum, pcnt, W1, b1, W2, b2, W3, b3,
                                           (float*)d_out);
}